// Round 18
// baseline (2650.801 us; speedup 1.0000x reference)
//
#include <hip/hip_runtime.h>
#include <stdint.h>

typedef __attribute__((ext_vector_type(8))) short short8;
typedef __attribute__((ext_vector_type(4))) float f32x4;
typedef __attribute__((ext_vector_type(4))) unsigned short ushort4v;
typedef unsigned long long u64;

__device__ inline unsigned short f2bf(float x) {
  union { float f; unsigned u; } v; v.f = x;
  unsigned r = (v.u + 0x7FFFu + ((v.u >> 16) & 1u)) >> 16;
  return (unsigned short)r;
}
__device__ inline float bf2f(unsigned short b) {
  union { unsigned u; float f; } v; v.u = ((unsigned)b) << 16;
  return v.f;
}
__device__ inline float fsig(float x) { return 1.f / (1.f + __expf(-x)); }

__device__ inline void gload_lds16(const void* g, void* l) {
  __builtin_amdgcn_global_load_lds(
      (const __attribute__((address_space(1))) unsigned int*)g,
      (__attribute__((address_space(3))) unsigned int*)l, 16, 0, 0);
}

// ---------- elementwise helpers ----------
__global__ void k_convert(const float* __restrict__ src, unsigned short* __restrict__ dst, int n4) {
  int i = blockIdx.x * blockDim.x + threadIdx.x;
  if (i < n4) {
    f32x4 v = *(const f32x4*)(src + (size_t)i * 4);
    ushort4v r;
    r.x = f2bf(v.x); r.y = f2bf(v.y); r.z = f2bf(v.z); r.w = f2bf(v.w);
    *(ushort4v*)(dst + (size_t)i * 4) = r;
  }
}

__global__ void k_bias(const float* __restrict__ a, const float* __restrict__ b,
                       float* __restrict__ o, int n) {
  int i = blockIdx.x * blockDim.x + threadIdx.x;
  if (i < n) o[i] = a[i] + b[i];
}

__global__ void k_init(unsigned short* __restrict__ h0, unsigned short* __restrict__ flags) {
  int i = blockIdx.x * blockDim.x + threadIdx.x;  // 65536 threads
  h0[i] = 0;                                      // ring slot 0 = h_{-1} = 0 (layout-independent)
  if (i < 1024) flags[i] = 0;                     // 4 groups x 256 per-wave u16 epochs
}

// ---------- bf16 GEMM: C = A @ B^T (+bias), A [M,K], B [N,K], all bf16, f32 accum ----------
// MODE 0: C bf16, natural row order (xe).
// MODE 1: C bf16 scattered to gx layout for the batch-group persist kernel:
//   thread identity tid4 = w*64 + b*4 + q, elem s:
//   idx = t*262144 + g*65536 + gt*1024 + tid4*4 + s
template <int MODE>
__global__ __launch_bounds__(256) void k_gemm_bt(
    const unsigned short* __restrict__ A,
    const unsigned short* __restrict__ Bm,
    const float* __restrict__ bias,
    unsigned short* __restrict__ C,
    int M, int N, int K) {
  __shared__ unsigned short As[128 * 32];
  __shared__ unsigned short Bs[128 * 32];
  const int tid = threadIdx.x;
  const int m0 = blockIdx.y * 128, n0 = blockIdx.x * 128;
  const int lane = tid & 63, w = tid >> 6;
  const int wm = (w >> 1) * 64, wn = (w & 1) * 64;

  f32x4 acc[4][4] = {};

  const int ar0 = tid >> 2;
  const int ak = (tid & 3) * 8;
  const unsigned short* Ag0 = A + (size_t)(m0 + ar0) * K + ak;
  const unsigned short* Ag1 = A + (size_t)(m0 + 64 + ar0) * K + ak;
  const unsigned short* Bg0 = Bm + (size_t)(n0 + ar0) * K + ak;
  const unsigned short* Bg1 = Bm + (size_t)(n0 + 64 + ar0) * K + ak;
  unsigned short* Al = As + tid * 8;
  unsigned short* Bl = Bs + tid * 8;

  const int lr = lane & 15, lk = (lane >> 4) * 8;

  for (int k0 = 0; k0 < K; k0 += 32) {
    gload_lds16(Ag0 + k0, Al);
    gload_lds16(Ag1 + k0, Al + 2048);
    gload_lds16(Bg0 + k0, Bl);
    gload_lds16(Bg1 + k0, Bl + 2048);
    __syncthreads();
    short8 a[4], b[4];
#pragma unroll
    for (int i = 0; i < 4; i++) a[i] = *(const short8*)&As[(wm + i * 16 + lr) * 32 + lk];
#pragma unroll
    for (int j = 0; j < 4; j++) b[j] = *(const short8*)&Bs[(wn + j * 16 + lr) * 32 + lk];
#pragma unroll
    for (int i = 0; i < 4; i++)
#pragma unroll
      for (int j = 0; j < 4; j++)
        acc[i][j] = __builtin_amdgcn_mfma_f32_16x16x32_bf16(a[i], b[j], acc[i][j], 0, 0, 0);
    __syncthreads();
  }

  const int lq = (lane >> 4) * 4;
#pragma unroll
  for (int j = 0; j < 4; j++) {
    int col = n0 + wn + j * 16 + lr;
    float bv = bias[col];
#pragma unroll
    for (int i = 0; i < 4; i++) {
      int rowb = m0 + wm + i * 16 + lq;
#pragma unroll
      for (int r = 0; r < 4; r++) {
        int row = rowb + r;
        float v = acc[i][j][r] + bv;
        if (MODE == 1) {
          int t = row & 511, bglob = row >> 9;
          int gg = bglob >> 4, bb = bglob & 15;
          int s = col >> 10, cc = col & 1023;
          int gtb = cc >> 4, cl = cc & 15;
          int wv = cl >> 2, qq = cl & 3;
          size_t idx = (size_t)t * 262144 + (size_t)gg * 65536 + (size_t)gtb * 1024
                     + (size_t)((wv * 64 + bb * 4 + qq) * 4 + s);
          C[idx] = f2bf(v);
        } else {
          C[(size_t)row * (size_t)N + col] = f2bf(v);
        }
      }
    }
  }
}

// ---------- persistent LSTM recurrence, batch-group partitioned ----------
// 256 blocks x 256 threads, 1 block/CU. Group g = (bid&3) owns batches
// [16g,16g+16); block gt = bid>>2 owns cols [gt*16,gt*16+16).
// Wave w: cols [gt*16+w*4,+4), all 4 gates; W rows in 32 named short8 regs.
// hring group-slot CONTENT is k-MAJOR: byte = kchunk*256 + row*16 + (col&7)*2.
// PER-WAVE FLAGS + PER-WAVE TAIL: each producer wave publishes its 4 cols,
// waits its OWN vmcnt(0) ack, lane0 stores flag[g][gt*4+w]. No fence/barrier
// in the tail. Consumer wave w̄ lane l polls exactly one u16 (producer
// gt'=16w̄+(l>>2), w'=l&3). Hs is DOUBLE-BUFFERED (intra-block skew <= 1 step
// without the tail barrier); the single post-stage __syncthreads remains.
#define R32(F) F(0) F(1) F(2) F(3) F(4) F(5) F(6) F(7) \
               F(8) F(9) F(10) F(11) F(12) F(13) F(14) F(15) \
               F(16) F(17) F(18) F(19) F(20) F(21) F(22) F(23) \
               F(24) F(25) F(26) F(27) F(28) F(29) F(30) F(31)
#define WDECL(i) short8 w##i;
#define WLOAD(i) asm volatile("global_load_dwordx4 %0, %1, off offset:%c2" \
                              : "=v"(w##i) : "v"(wbase), "i"((i) * 64));
// RING=512: h fragment from k-major LDS (lane base lB = hi*256 + lr*16 bytes)
#define MFH(i, ACC) { \
    short8 a_ = *(const short8*)(HsB + lB + (i) * 1024); \
    ACC = __builtin_amdgcn_mfma_f32_16x16x32_bf16(a_, w##i, ACC, 0, 0, 0); }
// RING=2 fallback: L2-bypassing atomic loads (plain layout)
#define MF2(i, ACC) { \
    union { u64 d[2]; short8 s; } u_; \
    u_.d[0] = __hip_atomic_load((const u64*)(hrow2 + (i) * 32), __ATOMIC_RELAXED, __HIP_MEMORY_SCOPE_AGENT); \
    u_.d[1] = __hip_atomic_load((const u64*)(hrow2 + (i) * 32 + 4), __ATOMIC_RELAXED, __HIP_MEMORY_SCOPE_AGENT); \
    ACC = __builtin_amdgcn_mfma_f32_16x16x32_bf16(u_.s, w##i, ACC, 0, 0, 0); }

template <int RING>
__global__ __launch_bounds__(256, 1) void k_persist(
    const unsigned short* __restrict__ gx3,   // scattered gate inputs (see GEMM MODE1)
    const unsigned short* __restrict__ Whh,   // [4096,1024] bf16
    unsigned short* __restrict__ hring,       // RING slots; k-major content if RING=512
    unsigned short* __restrict__ flags,       // [4][256] per-wave u16 epochs
    float* __restrict__ out,                  // [64][512][1024] f32
    float* __restrict__ hout,                 // [64][1024] f32
    float* __restrict__ cout) {               // [64][1024] f32
  __shared__ unsigned short Hs[2][16384];     // 2 x 32 KB group-h stage (k-major)
  __shared__ float Gs[4][16 * 17 + 4];        // per-wave gate buffers

  const int tid = threadIdx.x;
  const int g = blockIdx.x & 3, gt = blockIdx.x >> 2;
  const int lane = tid & 63, w = tid >> 6;
  const int lr = lane & 15, hi = lane >> 4;

  // ---- W_hh slice in named registers
  const int grow = (lr >> 2) * 1024 + gt * 16 + w * 4 + (lr & 3);
  const unsigned short* wbase = Whh + (size_t)grow * 1024 + hi * 8;
  R32(WDECL)
  R32(WLOAD)
  asm volatile("s_waitcnt vmcnt(0)" ::: "memory");
  __builtin_amdgcn_sched_barrier(0);

  // ---- cell identity: lane = cb*4 + cq (batch cb, col quad-offset cq)
  const int cb = lane >> 2, cq = lane & 3;
  const int col = gt * 16 + w * 4 + cq;
  const int brow = g * 16 + cb;               // global batch row
  float c_reg = 0.f;

  // gx: per (t, g, gt): 256 u64; thread tid's u64 = its 4 gate values (elem = s)
  const u64* gbase = (const u64*)gx3 + (size_t)g * 16384 + (size_t)gt * 256;
  u64 gv = gbase[tid];  // t = 0

  const int lB = hi * 256 + lr * 16;          // k-major lane byte base

  // per-wave poll: lane l covers producer (gt' = 16w + (l>>2), w' = l&3)
  const unsigned short* fpw = flags + g * 256 + w * 64 + lane;

  for (int t = 0; t < 512; ++t) {
    f32x4 ac0 = {}, ac1 = {}, ac2 = {}, ac3 = {};
    if (RING == 2) {
      // full-group poll (wave 0) + barrier, then direct atomic loads
      if (w == 0) {
        const u64* fp = (const u64*)flags + g * 16 + lane;  // lanes 0..15 valid
        for (;;) {
          bool ok = true;
          if (lane < 16) {
            u64 f = __hip_atomic_load(fp, __ATOMIC_RELAXED, __HIP_MEMORY_SCOPE_AGENT);
            ok = ((int)(f & 0xFFFF) >= t) && ((int)((f >> 16) & 0xFFFF) >= t) &&
                 ((int)((f >> 32) & 0xFFFF) >= t) && ((int)(f >> 48) >= t);
          }
          if (__all(ok)) break;
        }
      }
      __syncthreads();
      __builtin_amdgcn_sched_barrier(0);
      const unsigned short* hrow2 = hring + (size_t)(t & 1) * 65536
                                  + (size_t)(g * 16 + lr) * 1024 + hi * 8;
      MF2(0, ac0)  MF2(1, ac1)  MF2(2, ac2)  MF2(3, ac3)
      MF2(4, ac0)  MF2(5, ac1)  MF2(6, ac2)  MF2(7, ac3)
      MF2(8, ac0)  MF2(9, ac1)  MF2(10, ac2) MF2(11, ac3)
      MF2(12, ac0) MF2(13, ac1) MF2(14, ac2) MF2(15, ac3)
      MF2(16, ac0) MF2(17, ac1) MF2(18, ac2) MF2(19, ac3)
      MF2(20, ac0) MF2(21, ac1) MF2(22, ac2) MF2(23, ac3)
      MF2(24, ac0) MF2(25, ac1) MF2(26, ac2) MF2(27, ac3)
      MF2(28, ac0) MF2(29, ac1) MF2(30, ac2) MF2(31, ac3)
    } else {
      // 1. per-wave poll: one u16 per lane (this wave's 16 producers x 4 waves)
      for (;;) {
        unsigned short f = __hip_atomic_load(fpw, __ATOMIC_RELAXED, __HIP_MEMORY_SCOPE_AGENT);
        if (__all((int)f >= t)) break;
      }
      __builtin_amdgcn_sched_barrier(0);
      // 2. stage this wave's 8KB into Hs[t&1] (IDENTITY copy; k-major content)
      unsigned short* Hcur = Hs[t & 1];
      const char* HsB = (const char*)Hcur;
      const unsigned short* hsrc = hring + (size_t)t * 65536 + (size_t)g * 16384;
#pragma unroll
      for (int i = 0; i < 8; ++i) {
        int ch = w * 512 + i * 64;            // wave-uniform chunk base
        gload_lds16(hsrc + ((size_t)ch + lane) * 8, Hcur + (size_t)ch * 8);
      }
      asm volatile("s_waitcnt vmcnt(0)" ::: "memory");
      __builtin_amdgcn_sched_barrier(0);
      __syncthreads();                        // full-block rendezvous: all staged
      MFH(0, ac0)  MFH(1, ac1)  MFH(2, ac2)  MFH(3, ac3)
      MFH(4, ac0)  MFH(5, ac1)  MFH(6, ac2)  MFH(7, ac3)
      MFH(8, ac0)  MFH(9, ac1)  MFH(10, ac2) MFH(11, ac3)
      MFH(12, ac0) MFH(13, ac1) MFH(14, ac2) MFH(15, ac3)
      MFH(16, ac0) MFH(17, ac1) MFH(18, ac2) MFH(19, ac3)
      MFH(20, ac0) MFH(21, ac1) MFH(22, ac2) MFH(23, ac3)
      MFH(24, ac0) MFH(25, ac1) MFH(26, ac2) MFH(27, ac3)
      MFH(28, ac0) MFH(29, ac1) MFH(30, ac2) MFH(31, ac3)
    }
    f32x4 accs = (ac0 + ac1) + (ac2 + ac3);

    // 3. stage gates (intra-wave): Gs[w][b*17 + lr], b = hi*4+r; lr = s*4+q2
#pragma unroll
    for (int r = 0; r < 4; ++r)
      Gs[w][(hi * 4 + r) * 17 + lr] = accs[r];
    asm volatile("s_waitcnt lgkmcnt(0)" ::: "memory");
    __builtin_amdgcn_sched_barrier(0);

    // 4. cell update for (cb, col): gates from own wave's Gs + gx
    float gi = Gs[w][cb * 17 + 0 + cq]  + bf2f((unsigned short)(gv));
    float gf = Gs[w][cb * 17 + 4 + cq]  + bf2f((unsigned short)(gv >> 16));
    float gg = Gs[w][cb * 17 + 8 + cq]  + bf2f((unsigned short)(gv >> 32));
    float go = Gs[w][cb * 17 + 12 + cq] + bf2f((unsigned short)(gv >> 48));
    float i_ = fsig(gi);
    float f_ = fsig(gf);
    float g_ = tanhf(gg);
    float o_ = fsig(go);
    float cn = f_ * c_reg + i_ * g_;
    float hn = o_ * tanhf(cn);
    c_reg = cn;

    if (t == 511) {
      __builtin_nontemporal_store(hn, &out[((size_t)brow * 512 + t) * 1024 + col]);
      hout[(size_t)brow * 1024 + col] = hn;
      cout[(size_t)brow * 1024 + col] = cn;
    } else {
      // publish h_t: quad packs 4 cols into one u64, write-through, K-MAJOR addr
      unsigned hu = f2bf(hn);
      unsigned v0 = __shfl(hu, (lane & ~3) + 0);
      unsigned v1 = __shfl(hu, (lane & ~3) + 1);
      unsigned v2 = __shfl(hu, (lane & ~3) + 2);
      unsigned v3 = __shfl(hu, (lane & ~3) + 3);
      if ((lane & 3) == 0) {
        u64 pack = (u64)(v0 & 0xFFFF) | ((u64)(v1 & 0xFFFF) << 16)
                 | ((u64)(v2 & 0xFFFF) << 32) | ((u64)(v3 & 0xFFFF) << 48);
        u64* hp;
        if (RING == 2) {
          hp = (u64*)(hring + (size_t)((t + 1) & 1) * 65536
                      + (size_t)brow * 1024 + gt * 16 + w * 4);
        } else {
          // k-major: elem = kchunk*128 + cb*8 + (w&1)*4, kchunk = gt*2 + (w>>1)
          size_t e = (size_t)(gt * 2 + (w >> 1)) * 128 + (size_t)cb * 8 + (size_t)(w & 1) * 4;
          hp = (u64*)(hring + (size_t)(t + 1) * 65536 + (size_t)g * 16384 + e);
        }
        __hip_atomic_store(hp, pack, __ATOMIC_RELAXED, __HIP_MEMORY_SCOPE_AGENT);
      }
      if (RING == 2) {
        __threadfence_block();
        __syncthreads();
        if (tid == 0)
          __hip_atomic_store(&flags[g * 64 + gt], (unsigned short)(t + 1),
                             __ATOMIC_RELAXED, __HIP_MEMORY_SCOPE_AGENT);
      } else {
        // per-wave tail: own ack only, then per-wave flag; no block barrier
        asm volatile("s_waitcnt vmcnt(0)" ::: "memory");
        __builtin_amdgcn_sched_barrier(0);
        if (lane == 0)
          __hip_atomic_store(&flags[g * 256 + gt * 4 + w], (unsigned short)(t + 1),
                             __ATOMIC_RELAXED, __HIP_MEMORY_SCOPE_AGENT);
      }
      // out store + next-gx prefetch AFTER the handshake
      __builtin_nontemporal_store(hn, &out[((size_t)brow * 512 + t) * 1024 + col]);
      gv = gbase[(size_t)(t + 1) * 65536 + tid];
    }
  }
}
#undef MF2
#undef MFH
#undef WLOAD
#undef WDECL
#undef R32

extern "C" void kernel_launch(void* const* d_in, const int* in_sizes, int n_in,
                              void* d_out, int out_size, void* d_ws, size_t ws_size,
                              hipStream_t stream) {
  const float* x = (const float*)d_in[0];
  const float* W_emb = (const float*)d_in[1];
  const float* b_emb = (const float*)d_in[2];
  const float* W_ih = (const float*)d_in[3];
  const float* W_hh = (const float*)d_in[4];
  const float* b_ih = (const float*)d_in[5];
  const float* b_hh = (const float*)d_in[6];

  char* ws = (char*)d_ws;
  unsigned short* x_bf    = (unsigned short*)(ws + 0);           // 16,777,216 B
  unsigned short* Wemb_bf = (unsigned short*)(ws + 16777216);    // 262,144 B
  unsigned short* Wih_bf  = (unsigned short*)(ws + 17039360);    // 4,194,304 B
  unsigned short* Whh_bf  = (unsigned short*)(ws + 21233664);    // 8,388,608 B
  float* bias_sum         = (float*)(ws + 29622272);             // 16,384 B
  unsigned short* xe      = (unsigned short*)(ws + 29638656);    // 33,554,432 B
  unsigned short* gx3     = (unsigned short*)(ws + 63193088);    // 268,435,456 B
  unsigned short* flags   = (unsigned short*)(ws + 331628544);   // 4,096 B (2 KB used)
  unsigned short* hring   = (unsigned short*)(ws + 331632640);   // RING*131,072 B

  const size_t need_ring = 331632640ull + 512ull * 131072ull;    // ~398.7 MB
  const bool big = (ws_size >= need_ring);

  float* out = (float*)d_out;
  float* hout = out + (size_t)64 * 512 * 1024;
  float* cout = hout + 65536;

  k_convert<<<8192, 256, 0, stream>>>(x, x_bf, 2097152);
  k_convert<<<128, 256, 0, stream>>>(W_emb, Wemb_bf, 32768);
  k_convert<<<2048, 256, 0, stream>>>(W_ih, Wih_bf, 524288);
  k_convert<<<4096, 256, 0, stream>>>(W_hh, Whh_bf, 1048576);
  k_bias<<<16, 256, 0, stream>>>(b_ih, b_hh, bias_sum, 4096);
  k_init<<<256, 256, 0, stream>>>(hring, flags);

  // xe = x @ W_emb^T + b_emb : M=32768, N=512, K=256
  k_gemm_bt<0><<<dim3(4, 256), 256, 0, stream>>>(x_bf, Wemb_bf, b_emb, xe, 32768, 512, 256);
  // gx = xe @ W_ih^T + (b_ih+b_hh), scattered to batch-group persist layout
  k_gemm_bt<1><<<dim3(32, 256), 256, 0, stream>>>(xe, Wih_bf, bias_sum, gx3, 32768, 4096, 512);

  if (big)
    k_persist<512><<<256, 256, 0, stream>>>(gx3, Whh_bf, hring, flags, out, hout, cout);
  else
    k_persist<2><<<256, 256, 0, stream>>>(gx3, Whh_bf, hring, flags, out, hout, cout);
}

// Round 19
// 2143.880 us; speedup vs baseline: 1.2365x; 1.2365x over previous
//
#include <hip/hip_runtime.h>
#include <stdint.h>

typedef __attribute__((ext_vector_type(8))) short short8;
typedef __attribute__((ext_vector_type(4))) float f32x4;
typedef __attribute__((ext_vector_type(4))) unsigned short ushort4v;
typedef unsigned long long u64;

__device__ inline unsigned short f2bf(float x) {
  union { float f; unsigned u; } v; v.f = x;
  unsigned r = (v.u + 0x7FFFu + ((v.u >> 16) & 1u)) >> 16;
  return (unsigned short)r;
}
__device__ inline float bf2f(unsigned short b) {
  union { unsigned u; float f; } v; v.u = ((unsigned)b) << 16;
  return v.f;
}
__device__ inline float fsig(float x) { return 1.f / (1.f + __expf(-x)); }

__device__ inline void gload_lds16(const void* g, void* l) {
  __builtin_amdgcn_global_load_lds(
      (const __attribute__((address_space(1))) unsigned int*)g,
      (__attribute__((address_space(3))) unsigned int*)l, 16, 0, 0);
}

// ---------- elementwise helpers ----------
__global__ void k_convert(const float* __restrict__ src, unsigned short* __restrict__ dst, int n4) {
  int i = blockIdx.x * blockDim.x + threadIdx.x;
  if (i < n4) {
    f32x4 v = *(const f32x4*)(src + (size_t)i * 4);
    ushort4v r;
    r.x = f2bf(v.x); r.y = f2bf(v.y); r.z = f2bf(v.z); r.w = f2bf(v.w);
    *(ushort4v*)(dst + (size_t)i * 4) = r;
  }
}

__global__ void k_bias(const float* __restrict__ a, const float* __restrict__ b,
                       float* __restrict__ o, int n) {
  int i = blockIdx.x * blockDim.x + threadIdx.x;
  if (i < n) o[i] = a[i] + b[i];
}

__global__ void k_init(unsigned short* __restrict__ h0, unsigned short* __restrict__ flags) {
  int i = blockIdx.x * blockDim.x + threadIdx.x;  // 65536 threads
  h0[i] = 0;                                      // ring slot 0 = h_{-1} = 0 (layout-independent)
  if (i < 256) flags[i] = 0;                      // 4 groups x 64 u16 epochs
}

// ---------- bf16 GEMM: C = A @ B^T (+bias), A [M,K], B [N,K], all bf16, f32 accum ----------
// MODE 0: C bf16, natural row order (xe).
// MODE 1: C bf16 scattered to gx layout for the batch-group persist kernel;
//         XCD-aware bijective block swizzle (nwg % 8 == 0) for A-panel L2 reuse.
template <int MODE>
__global__ __launch_bounds__(256) void k_gemm_bt(
    const unsigned short* __restrict__ A,
    const unsigned short* __restrict__ Bm,
    const float* __restrict__ bias,
    unsigned short* __restrict__ C,
    int M, int N, int K) {
  __shared__ unsigned short As[128 * 32];
  __shared__ unsigned short Bs[128 * 32];
  const int tid = threadIdx.x;

  int bidx = blockIdx.x, bidy = blockIdx.y;
  if (MODE == 1) {
    int bid = blockIdx.y * gridDim.x + blockIdx.x;
    int cpx = (gridDim.x * gridDim.y) >> 3;      // nwg/8 (nwg divisible by 8)
    int swz = (bid & 7) * cpx + (bid >> 3);      // XCD-contiguous chunks
    bidy = swz / gridDim.x;
    bidx = swz % gridDim.x;
  }
  const int m0 = bidy * 128, n0 = bidx * 128;
  const int lane = tid & 63, w = tid >> 6;
  const int wm = (w >> 1) * 64, wn = (w & 1) * 64;

  f32x4 acc[4][4] = {};

  const int ar0 = tid >> 2;
  const int ak = (tid & 3) * 8;
  const unsigned short* Ag0 = A + (size_t)(m0 + ar0) * K + ak;
  const unsigned short* Ag1 = A + (size_t)(m0 + 64 + ar0) * K + ak;
  const unsigned short* Bg0 = Bm + (size_t)(n0 + ar0) * K + ak;
  const unsigned short* Bg1 = Bm + (size_t)(n0 + 64 + ar0) * K + ak;
  unsigned short* Al = As + tid * 8;
  unsigned short* Bl = Bs + tid * 8;

  const int lr = lane & 15, lk = (lane >> 4) * 8;

  for (int k0 = 0; k0 < K; k0 += 32) {
    gload_lds16(Ag0 + k0, Al);
    gload_lds16(Ag1 + k0, Al + 2048);
    gload_lds16(Bg0 + k0, Bl);
    gload_lds16(Bg1 + k0, Bl + 2048);
    __syncthreads();
    short8 a[4], b[4];
#pragma unroll
    for (int i = 0; i < 4; i++) a[i] = *(const short8*)&As[(wm + i * 16 + lr) * 32 + lk];
#pragma unroll
    for (int j = 0; j < 4; j++) b[j] = *(const short8*)&Bs[(wn + j * 16 + lr) * 32 + lk];
#pragma unroll
    for (int i = 0; i < 4; i++)
#pragma unroll
      for (int j = 0; j < 4; j++)
        acc[i][j] = __builtin_amdgcn_mfma_f32_16x16x32_bf16(a[i], b[j], acc[i][j], 0, 0, 0);
    __syncthreads();
  }

  const int lq = (lane >> 4) * 4;
#pragma unroll
  for (int j = 0; j < 4; j++) {
    int col = n0 + wn + j * 16 + lr;
    float bv = bias[col];
#pragma unroll
    for (int i = 0; i < 4; i++) {
      int rowb = m0 + wm + i * 16 + lq;
#pragma unroll
      for (int r = 0; r < 4; r++) {
        int row = rowb + r;
        float v = acc[i][j][r] + bv;
        if (MODE == 1) {
          int t = row & 511, bglob = row >> 9;
          int gg = bglob >> 4, bb = bglob & 15;
          int s = col >> 10, cc = col & 1023;
          int gtb = cc >> 4, cl = cc & 15;
          int wv = cl >> 2, qq = cl & 3;
          size_t idx = (size_t)t * 262144 + (size_t)gg * 65536 + (size_t)gtb * 1024
                     + (size_t)((wv * 64 + bb * 4 + qq) * 4 + s);
          C[idx] = f2bf(v);
        } else {
          C[(size_t)row * (size_t)N + col] = f2bf(v);
        }
      }
    }
  }
}

// ---------- persistent LSTM recurrence, batch-group partitioned (R17 form) ----------
// 256 blocks x 256 threads, 1 block/CU. Group g = (bid&3) owns batches
// [16g,16g+16); block gt = bid>>2 owns cols [gt*16,gt*16+16).
// Wave w: cols [gt*16+w*4,+4), all 4 gates; W rows in 32 named short8 regs.
// hring group-slot CONTENT is k-MAJOR: byte = kchunk*256 + row*16 + (col&7)*2.
// PER-WAVE SUBSET POLL: wave w's staged bytes [w*8KB,+8KB) come from producers
// gt' in [w*16,(w+1)*16) -> wave polls only those 16 flags (4 u64), stages its
// 8KB as soon as they're ready; post-stage __syncthreads is the rendezvous.
#define R32(F) F(0) F(1) F(2) F(3) F(4) F(5) F(6) F(7) \
               F(8) F(9) F(10) F(11) F(12) F(13) F(14) F(15) \
               F(16) F(17) F(18) F(19) F(20) F(21) F(22) F(23) \
               F(24) F(25) F(26) F(27) F(28) F(29) F(30) F(31)
#define WDECL(i) short8 w##i;
#define WLOAD(i) asm volatile("global_load_dwordx4 %0, %1, off offset:%c2" \
                              : "=v"(w##i) : "v"(wbase), "i"((i) * 64));
// RING=512: h fragment from k-major LDS (lane base lB = hi*256 + lr*16 bytes)
#define MFH(i, ACC) { \
    short8 a_ = *(const short8*)(HsB + lB + (i) * 1024); \
    ACC = __builtin_amdgcn_mfma_f32_16x16x32_bf16(a_, w##i, ACC, 0, 0, 0); }
// RING=2 fallback: L2-bypassing atomic loads (plain layout)
#define MF2(i, ACC) { \
    union { u64 d[2]; short8 s; } u_; \
    u_.d[0] = __hip_atomic_load((const u64*)(hrow2 + (i) * 32), __ATOMIC_RELAXED, __HIP_MEMORY_SCOPE_AGENT); \
    u_.d[1] = __hip_atomic_load((const u64*)(hrow2 + (i) * 32 + 4), __ATOMIC_RELAXED, __HIP_MEMORY_SCOPE_AGENT); \
    ACC = __builtin_amdgcn_mfma_f32_16x16x32_bf16(u_.s, w##i, ACC, 0, 0, 0); }

template <int RING>
__global__ __launch_bounds__(256, 1) void k_persist(
    const unsigned short* __restrict__ gx3,   // scattered gate inputs (see GEMM MODE1)
    const unsigned short* __restrict__ Whh,   // [4096,1024] bf16
    unsigned short* __restrict__ hring,       // RING slots; k-major content if RING=512
    unsigned short* __restrict__ flags,       // [4][64] u16 epochs
    float* __restrict__ out,                  // [64][512][1024] f32
    float* __restrict__ hout,                 // [64][1024] f32
    float* __restrict__ cout) {               // [64][1024] f32
  __shared__ unsigned short Hs[16384];        // 32 KB group-h stage (k-major content)
  __shared__ float Gs[4][16 * 17 + 4];        // per-wave gate buffers

  const int tid = threadIdx.x;
  const int g = blockIdx.x & 3, gt = blockIdx.x >> 2;
  const int lane = tid & 63, w = tid >> 6;
  const int lr = lane & 15, hi = lane >> 4;

  // ---- W_hh slice in named registers
  const int grow = (lr >> 2) * 1024 + gt * 16 + w * 4 + (lr & 3);
  const unsigned short* wbase = Whh + (size_t)grow * 1024 + hi * 8;
  R32(WDECL)
  R32(WLOAD)
  asm volatile("s_waitcnt vmcnt(0)" ::: "memory");
  __builtin_amdgcn_sched_barrier(0);

  // ---- cell identity: lane = cb*4 + cq (batch cb, col quad-offset cq)
  const int cb = lane >> 2, cq = lane & 3;
  const int col = gt * 16 + w * 4 + cq;
  const int brow = g * 16 + cb;               // global batch row
  float c_reg = 0.f;

  // gx: per (t, g, gt): 256 u64; thread tid's u64 = its 4 gate values (elem = s)
  const u64* gbase = (const u64*)gx3 + (size_t)g * 16384 + (size_t)gt * 256;
  u64 gv = gbase[tid];  // t = 0

  const char* HsB = (const char*)Hs;
  const int lB = hi * 256 + lr * 16;          // k-major lane byte base

  // per-wave poll pointer: wave w needs flags of producers [w*16,(w+1)*16)
  const u64* fpw = (const u64*)flags + g * 16 + w * 4 + (lane & 3);

  for (int t = 0; t < 512; ++t) {
    f32x4 ac0 = {}, ac1 = {}, ac2 = {}, ac3 = {};
    if (RING == 2) {
      // full-group poll (wave 0) + barrier, then direct atomic loads
      if (w == 0) {
        const u64* fp = (const u64*)flags + g * 16 + lane;  // lanes 0..15 valid
        for (;;) {
          bool ok = true;
          if (lane < 16) {
            u64 f = __hip_atomic_load(fp, __ATOMIC_RELAXED, __HIP_MEMORY_SCOPE_AGENT);
            ok = ((int)(f & 0xFFFF) >= t) && ((int)((f >> 16) & 0xFFFF) >= t) &&
                 ((int)((f >> 32) & 0xFFFF) >= t) && ((int)(f >> 48) >= t);
          }
          if (__all(ok)) break;
        }
      }
      __syncthreads();
      __builtin_amdgcn_sched_barrier(0);
      const unsigned short* hrow2 = hring + (size_t)(t & 1) * 65536
                                  + (size_t)(g * 16 + lr) * 1024 + hi * 8;
      MF2(0, ac0)  MF2(1, ac1)  MF2(2, ac2)  MF2(3, ac3)
      MF2(4, ac0)  MF2(5, ac1)  MF2(6, ac2)  MF2(7, ac3)
      MF2(8, ac0)  MF2(9, ac1)  MF2(10, ac2) MF2(11, ac3)
      MF2(12, ac0) MF2(13, ac1) MF2(14, ac2) MF2(15, ac3)
      MF2(16, ac0) MF2(17, ac1) MF2(18, ac2) MF2(19, ac3)
      MF2(20, ac0) MF2(21, ac1) MF2(22, ac2) MF2(23, ac3)
      MF2(24, ac0) MF2(25, ac1) MF2(26, ac2) MF2(27, ac3)
      MF2(28, ac0) MF2(29, ac1) MF2(30, ac2) MF2(31, ac3)
    } else {
      // 1. per-wave subset poll: only this wave's 16 producers (4 u64)
      for (;;) {
        u64 f = __hip_atomic_load(fpw, __ATOMIC_RELAXED, __HIP_MEMORY_SCOPE_AGENT);
        bool ok = ((int)(f & 0xFFFF) >= t) && ((int)((f >> 16) & 0xFFFF) >= t) &&
                  ((int)((f >> 32) & 0xFFFF) >= t) && ((int)(f >> 48) >= t);
        if (__all(ok)) break;
      }
      __builtin_amdgcn_sched_barrier(0);
      // 2. stage this wave's 8KB (IDENTITY copy; content already k-major)
      const unsigned short* hsrc = hring + (size_t)t * 65536 + (size_t)g * 16384;
#pragma unroll
      for (int i = 0; i < 8; ++i) {
        int ch = w * 512 + i * 64;            // wave-uniform chunk base
        gload_lds16(hsrc + ((size_t)ch + lane) * 8, Hs + (size_t)ch * 8);
      }
      asm volatile("s_waitcnt vmcnt(0)" ::: "memory");
      __builtin_amdgcn_sched_barrier(0);
      __syncthreads();                        // full-block rendezvous: all staged
      MFH(0, ac0)  MFH(1, ac1)  MFH(2, ac2)  MFH(3, ac3)
      MFH(4, ac0)  MFH(5, ac1)  MFH(6, ac2)  MFH(7, ac3)
      MFH(8, ac0)  MFH(9, ac1)  MFH(10, ac2) MFH(11, ac3)
      MFH(12, ac0) MFH(13, ac1) MFH(14, ac2) MFH(15, ac3)
      MFH(16, ac0) MFH(17, ac1) MFH(18, ac2) MFH(19, ac3)
      MFH(20, ac0) MFH(21, ac1) MFH(22, ac2) MFH(23, ac3)
      MFH(24, ac0) MFH(25, ac1) MFH(26, ac2) MFH(27, ac3)
      MFH(28, ac0) MFH(29, ac1) MFH(30, ac2) MFH(31, ac3)
    }
    f32x4 accs = (ac0 + ac1) + (ac2 + ac3);

    // 3. stage gates (intra-wave): Gs[w][b*17 + lr], b = hi*4+r; lr = s*4+q2
#pragma unroll
    for (int r = 0; r < 4; ++r)
      Gs[w][(hi * 4 + r) * 17 + lr] = accs[r];
    asm volatile("s_waitcnt lgkmcnt(0)" ::: "memory");
    __builtin_amdgcn_sched_barrier(0);

    // 4. cell update for (cb, col): gates from own wave's Gs + gx
    float gi = Gs[w][cb * 17 + 0 + cq]  + bf2f((unsigned short)(gv));
    float gf = Gs[w][cb * 17 + 4 + cq]  + bf2f((unsigned short)(gv >> 16));
    float gg = Gs[w][cb * 17 + 8 + cq]  + bf2f((unsigned short)(gv >> 32));
    float go = Gs[w][cb * 17 + 12 + cq] + bf2f((unsigned short)(gv >> 48));
    float i_ = fsig(gi);
    float f_ = fsig(gf);
    float g_ = tanhf(gg);
    float o_ = fsig(go);
    float cn = f_ * c_reg + i_ * g_;
    float hn = o_ * tanhf(cn);
    c_reg = cn;

    if (t == 511) {
      __builtin_nontemporal_store(hn, &out[((size_t)brow * 512 + t) * 1024 + col]);
      hout[(size_t)brow * 1024 + col] = hn;
      cout[(size_t)brow * 1024 + col] = cn;
    } else {
      // publish h_t: quad packs 4 cols into one u64, write-through, K-MAJOR addr
      unsigned hu = f2bf(hn);
      unsigned v0 = __shfl(hu, (lane & ~3) + 0);
      unsigned v1 = __shfl(hu, (lane & ~3) + 1);
      unsigned v2 = __shfl(hu, (lane & ~3) + 2);
      unsigned v3 = __shfl(hu, (lane & ~3) + 3);
      if ((lane & 3) == 0) {
        u64 pack = (u64)(v0 & 0xFFFF) | ((u64)(v1 & 0xFFFF) << 16)
                 | ((u64)(v2 & 0xFFFF) << 32) | ((u64)(v3 & 0xFFFF) << 48);
        u64* hp;
        if (RING == 2) {
          hp = (u64*)(hring + (size_t)((t + 1) & 1) * 65536
                      + (size_t)brow * 1024 + gt * 16 + w * 4);
        } else {
          // k-major: elem = kchunk*128 + cb*8 + (w&1)*4, kchunk = gt*2 + (w>>1)
          size_t e = (size_t)(gt * 2 + (w >> 1)) * 128 + (size_t)cb * 8 + (size_t)(w & 1) * 4;
          hp = (u64*)(hring + (size_t)(t + 1) * 65536 + (size_t)g * 16384 + e);
        }
        __hip_atomic_store(hp, pack, __ATOMIC_RELAXED, __HIP_MEMORY_SCOPE_AGENT);
      }
      __syncthreads();        // barrier drains vmcnt for all waves (fence redundant)
      if (tid == 0)           // RELAXED u16 flag store (group-local)
        __hip_atomic_store(&flags[g * 64 + gt], (unsigned short)(t + 1),
                           __ATOMIC_RELAXED, __HIP_MEMORY_SCOPE_AGENT);
      // out store + next-gx prefetch AFTER the handshake
      __builtin_nontemporal_store(hn, &out[((size_t)brow * 512 + t) * 1024 + col]);
      gv = gbase[(size_t)(t + 1) * 65536 + tid];
    }
  }
}
#undef MF2
#undef MFH
#undef WLOAD
#undef WDECL
#undef R32

extern "C" void kernel_launch(void* const* d_in, const int* in_sizes, int n_in,
                              void* d_out, int out_size, void* d_ws, size_t ws_size,
                              hipStream_t stream) {
  const float* x = (const float*)d_in[0];
  const float* W_emb = (const float*)d_in[1];
  const float* b_emb = (const float*)d_in[2];
  const float* W_ih = (const float*)d_in[3];
  const float* W_hh = (const float*)d_in[4];
  const float* b_ih = (const float*)d_in[5];
  const float* b_hh = (const float*)d_in[6];

  char* ws = (char*)d_ws;
  unsigned short* x_bf    = (unsigned short*)(ws + 0);           // 16,777,216 B
  unsigned short* Wemb_bf = (unsigned short*)(ws + 16777216);    // 262,144 B
  unsigned short* Wih_bf  = (unsigned short*)(ws + 17039360);    // 4,194,304 B
  unsigned short* Whh_bf  = (unsigned short*)(ws + 21233664);    // 8,388,608 B
  float* bias_sum         = (float*)(ws + 29622272);             // 16,384 B
  unsigned short* xe      = (unsigned short*)(ws + 29638656);    // 33,554,432 B
  unsigned short* gx3     = (unsigned short*)(ws + 63193088);    // 268,435,456 B
  unsigned short* flags   = (unsigned short*)(ws + 331628544);   // 4,096 B (512 B used)
  unsigned short* hring   = (unsigned short*)(ws + 331632640);   // RING*131,072 B

  const size_t need_ring = 331632640ull + 512ull * 131072ull;    // ~398.7 MB
  const bool big = (ws_size >= need_ring);

  float* out = (float*)d_out;
  float* hout = out + (size_t)64 * 512 * 1024;
  float* cout = hout + 65536;

  k_convert<<<8192, 256, 0, stream>>>(x, x_bf, 2097152);
  k_convert<<<128, 256, 0, stream>>>(W_emb, Wemb_bf, 32768);
  k_convert<<<2048, 256, 0, stream>>>(W_ih, Wih_bf, 524288);
  k_convert<<<4096, 256, 0, stream>>>(W_hh, Whh_bf, 1048576);
  k_bias<<<16, 256, 0, stream>>>(b_ih, b_hh, bias_sum, 4096);
  k_init<<<256, 256, 0, stream>>>(hring, flags);

  // xe = x @ W_emb^T + b_emb : M=32768, N=512, K=256
  k_gemm_bt<0><<<dim3(4, 256), 256, 0, stream>>>(x_bf, Wemb_bf, b_emb, xe, 32768, 512, 256);
  // gx = xe @ W_ih^T + (b_ih+b_hh), scattered to batch-group persist layout
  k_gemm_bt<1><<<dim3(32, 256), 256, 0, stream>>>(xe, Wih_bf, bias_sum, gx3, 32768, 4096, 512);

  if (big)
    k_persist<512><<<256, 256, 0, stream>>>(gx3, Whh_bf, hring, flags, out, hout, cout);
  else
    k_persist<2><<<256, 256, 0, stream>>>(gx3, Whh_bf, hring, flags, out, hout, cout);
}

// Round 20
// 2052.351 us; speedup vs baseline: 1.2916x; 1.0446x over previous
//
#include <hip/hip_runtime.h>
#include <stdint.h>

typedef __attribute__((ext_vector_type(8))) short short8;
typedef __attribute__((ext_vector_type(4))) float f32x4;
typedef __attribute__((ext_vector_type(4))) unsigned short ushort4v;
typedef unsigned long long u64;

__device__ inline unsigned short f2bf(float x) {
  union { float f; unsigned u; } v; v.f = x;
  unsigned r = (v.u + 0x7FFFu + ((v.u >> 16) & 1u)) >> 16;
  return (unsigned short)r;
}
__device__ inline float bf2f(unsigned short b) {
  union { unsigned u; float f; } v; v.u = ((unsigned)b) << 16;
  return v.f;
}
__device__ inline float fsig(float x) { return 1.f / (1.f + __expf(-x)); }

__device__ inline void gload_lds16(const void* g, void* l) {
  __builtin_amdgcn_global_load_lds(
      (const __attribute__((address_space(1))) unsigned int*)g,
      (__attribute__((address_space(3))) unsigned int*)l, 16, 0, 0);
}

// ---------- elementwise helpers ----------
__global__ void k_convert(const float* __restrict__ src, unsigned short* __restrict__ dst, int n4) {
  int i = blockIdx.x * blockDim.x + threadIdx.x;
  if (i < n4) {
    f32x4 v = *(const f32x4*)(src + (size_t)i * 4);
    ushort4v r;
    r.x = f2bf(v.x); r.y = f2bf(v.y); r.z = f2bf(v.z); r.w = f2bf(v.w);
    *(ushort4v*)(dst + (size_t)i * 4) = r;
  }
}

// W_emb [512,256] f32 -> WembT [256,512] bf16
__global__ void k_temb(const float* __restrict__ We, unsigned short* __restrict__ WT) {
  int o = blockIdx.x * blockDim.x + threadIdx.x;  // 131072
  int r = o >> 9, e = o & 511;
  WT[o] = f2bf(We[e * 256 + r]);
}

// b_comb[g] = sum_e W_ih[g,e]*b_emb[e] + b_ih[g] + b_hh[g]   (pure f32)
__global__ void k_bcomb(const float* __restrict__ Wih, const float* __restrict__ b_emb,
                        const float* __restrict__ b_ih, const float* __restrict__ b_hh,
                        float* __restrict__ out) {
  int g = blockIdx.x * blockDim.x + threadIdx.x;  // 4096
  const float* row = Wih + (size_t)g * 512;
  float s = 0.f;
  for (int e = 0; e < 512; ++e) s += row[e] * b_emb[e];
  out[g] = s + b_ih[g] + b_hh[g];
}

__global__ void k_init(unsigned short* __restrict__ h0, unsigned short* __restrict__ flags,
                       float* __restrict__ zerob) {
  int i = blockIdx.x * blockDim.x + threadIdx.x;  // 65536 threads
  h0[i] = 0;                                      // ring slot 0 = h_{-1} = 0
  if (i < 256) { flags[i] = 0; zerob[i] = 0.f; }
}

// ---------- bf16 GEMM: C = A @ B^T (+bias), A [M,K], B [N,K], all bf16, f32 accum ----------
// MODE 0: C bf16, natural row order.
// MODE 1: C bf16 scattered to gx layout for the batch-group persist kernel;
//         XCD-aware block swizzle (nwg % 8 == 0).
template <int MODE>
__global__ __launch_bounds__(256) void k_gemm_bt(
    const unsigned short* __restrict__ A,
    const unsigned short* __restrict__ Bm,
    const float* __restrict__ bias,
    unsigned short* __restrict__ C,
    int M, int N, int K) {
  __shared__ unsigned short As[128 * 32];
  __shared__ unsigned short Bs[128 * 32];
  const int tid = threadIdx.x;

  int bidx = blockIdx.x, bidy = blockIdx.y;
  if (MODE == 1) {
    int bid = blockIdx.y * gridDim.x + blockIdx.x;
    int cpx = (gridDim.x * gridDim.y) >> 3;      // nwg/8 (nwg divisible by 8)
    int swz = (bid & 7) * cpx + (bid >> 3);      // XCD-contiguous chunks
    bidy = swz / gridDim.x;
    bidx = swz % gridDim.x;
  }
  const int m0 = bidy * 128, n0 = bidx * 128;
  const int lane = tid & 63, w = tid >> 6;
  const int wm = (w >> 1) * 64, wn = (w & 1) * 64;

  f32x4 acc[4][4] = {};

  const int ar0 = tid >> 2;
  const int ak = (tid & 3) * 8;
  const unsigned short* Ag0 = A + (size_t)(m0 + ar0) * K + ak;
  const unsigned short* Ag1 = A + (size_t)(m0 + 64 + ar0) * K + ak;
  const unsigned short* Bg0 = Bm + (size_t)(n0 + ar0) * K + ak;
  const unsigned short* Bg1 = Bm + (size_t)(n0 + 64 + ar0) * K + ak;
  unsigned short* Al = As + tid * 8;
  unsigned short* Bl = Bs + tid * 8;

  const int lr = lane & 15, lk = (lane >> 4) * 8;

  for (int k0 = 0; k0 < K; k0 += 32) {
    gload_lds16(Ag0 + k0, Al);
    gload_lds16(Ag1 + k0, Al + 2048);
    gload_lds16(Bg0 + k0, Bl);
    gload_lds16(Bg1 + k0, Bl + 2048);
    __syncthreads();
    short8 a[4], b[4];
#pragma unroll
    for (int i = 0; i < 4; i++) a[i] = *(const short8*)&As[(wm + i * 16 + lr) * 32 + lk];
#pragma unroll
    for (int j = 0; j < 4; j++) b[j] = *(const short8*)&Bs[(wn + j * 16 + lr) * 32 + lk];
#pragma unroll
    for (int i = 0; i < 4; i++)
#pragma unroll
      for (int j = 0; j < 4; j++)
        acc[i][j] = __builtin_amdgcn_mfma_f32_16x16x32_bf16(a[i], b[j], acc[i][j], 0, 0, 0);
    __syncthreads();
  }

  const int lq = (lane >> 4) * 4;
#pragma unroll
  for (int j = 0; j < 4; j++) {
    int col = n0 + wn + j * 16 + lr;
    float bv = bias[col];
#pragma unroll
    for (int i = 0; i < 4; i++) {
      int rowb = m0 + wm + i * 16 + lq;
#pragma unroll
      for (int r = 0; r < 4; r++) {
        int row = rowb + r;
        float v = acc[i][j][r] + bv;
        if (MODE == 1) {
          int t = row & 511, bglob = row >> 9;
          int gg = bglob >> 4, bb = bglob & 15;
          int s = col >> 10, cc = col & 1023;
          int gtb = cc >> 4, cl = cc & 15;
          int wv = cl >> 2, qq = cl & 3;
          size_t idx = (size_t)t * 262144 + (size_t)gg * 65536 + (size_t)gtb * 1024
                     + (size_t)((wv * 64 + bb * 4 + qq) * 4 + s);
          C[idx] = f2bf(v);
        } else {
          C[(size_t)row * (size_t)N + col] = f2bf(v);
        }
      }
    }
  }
}

// ---------- persistent LSTM recurrence, batch-group partitioned (R17/R19 form) ----------
#define R32(F) F(0) F(1) F(2) F(3) F(4) F(5) F(6) F(7) \
               F(8) F(9) F(10) F(11) F(12) F(13) F(14) F(15) \
               F(16) F(17) F(18) F(19) F(20) F(21) F(22) F(23) \
               F(24) F(25) F(26) F(27) F(28) F(29) F(30) F(31)
#define WDECL(i) short8 w##i;
#define WLOAD(i) asm volatile("global_load_dwordx4 %0, %1, off offset:%c2" \
                              : "=v"(w##i) : "v"(wbase), "i"((i) * 64));
#define MFH(i, ACC) { \
    short8 a_ = *(const short8*)(HsB + lB + (i) * 1024); \
    ACC = __builtin_amdgcn_mfma_f32_16x16x32_bf16(a_, w##i, ACC, 0, 0, 0); }
#define MF2(i, ACC) { \
    union { u64 d[2]; short8 s; } u_; \
    u_.d[0] = __hip_atomic_load((const u64*)(hrow2 + (i) * 32), __ATOMIC_RELAXED, __HIP_MEMORY_SCOPE_AGENT); \
    u_.d[1] = __hip_atomic_load((const u64*)(hrow2 + (i) * 32 + 4), __ATOMIC_RELAXED, __HIP_MEMORY_SCOPE_AGENT); \
    ACC = __builtin_amdgcn_mfma_f32_16x16x32_bf16(u_.s, w##i, ACC, 0, 0, 0); }

template <int RING>
__global__ __launch_bounds__(256, 1) void k_persist(
    const unsigned short* __restrict__ gx3,   // scattered gate inputs (see GEMM MODE1)
    const unsigned short* __restrict__ Whh,   // [4096,1024] bf16
    unsigned short* __restrict__ hring,       // RING slots; k-major content if RING=512
    unsigned short* __restrict__ flags,       // [4][64] u16 epochs
    float* __restrict__ out,                  // [64][512][1024] f32
    float* __restrict__ hout,                 // [64][1024] f32
    float* __restrict__ cout) {               // [64][1024] f32
  __shared__ unsigned short Hs[16384];        // 32 KB group-h stage (k-major content)
  __shared__ float Gs[4][16 * 17 + 4];        // per-wave gate buffers

  const int tid = threadIdx.x;
  const int g = blockIdx.x & 3, gt = blockIdx.x >> 2;
  const int lane = tid & 63, w = tid >> 6;
  const int lr = lane & 15, hi = lane >> 4;

  // ---- W_hh slice in named registers
  const int grow = (lr >> 2) * 1024 + gt * 16 + w * 4 + (lr & 3);
  const unsigned short* wbase = Whh + (size_t)grow * 1024 + hi * 8;
  R32(WDECL)
  R32(WLOAD)
  asm volatile("s_waitcnt vmcnt(0)" ::: "memory");
  __builtin_amdgcn_sched_barrier(0);

  // ---- cell identity: lane = cb*4 + cq (batch cb, col quad-offset cq)
  const int cb = lane >> 2, cq = lane & 3;
  const int col = gt * 16 + w * 4 + cq;
  const int brow = g * 16 + cb;               // global batch row
  float c_reg = 0.f;

  // gx: per (t, g, gt): 256 u64; thread tid's u64 = its 4 gate values (elem = s)
  const u64* gbase = (const u64*)gx3 + (size_t)g * 16384 + (size_t)gt * 256;
  u64 gv = gbase[tid];  // t = 0

  const char* HsB = (const char*)Hs;
  const int lB = hi * 256 + lr * 16;          // k-major lane byte base

  // per-wave poll pointer: wave w needs flags of producers [w*16,(w+1)*16)
  const u64* fpw = (const u64*)flags + g * 16 + w * 4 + (lane & 3);

  for (int t = 0; t < 512; ++t) {
    f32x4 ac0 = {}, ac1 = {}, ac2 = {}, ac3 = {};
    if (RING == 2) {
      if (w == 0) {
        const u64* fp = (const u64*)flags + g * 16 + lane;  // lanes 0..15 valid
        for (;;) {
          bool ok = true;
          if (lane < 16) {
            u64 f = __hip_atomic_load(fp, __ATOMIC_RELAXED, __HIP_MEMORY_SCOPE_AGENT);
            ok = ((int)(f & 0xFFFF) >= t) && ((int)((f >> 16) & 0xFFFF) >= t) &&
                 ((int)((f >> 32) & 0xFFFF) >= t) && ((int)(f >> 48) >= t);
          }
          if (__all(ok)) break;
        }
      }
      __syncthreads();
      __builtin_amdgcn_sched_barrier(0);
      const unsigned short* hrow2 = hring + (size_t)(t & 1) * 65536
                                  + (size_t)(g * 16 + lr) * 1024 + hi * 8;
      MF2(0, ac0)  MF2(1, ac1)  MF2(2, ac2)  MF2(3, ac3)
      MF2(4, ac0)  MF2(5, ac1)  MF2(6, ac2)  MF2(7, ac3)
      MF2(8, ac0)  MF2(9, ac1)  MF2(10, ac2) MF2(11, ac3)
      MF2(12, ac0) MF2(13, ac1) MF2(14, ac2) MF2(15, ac3)
      MF2(16, ac0) MF2(17, ac1) MF2(18, ac2) MF2(19, ac3)
      MF2(20, ac0) MF2(21, ac1) MF2(22, ac2) MF2(23, ac3)
      MF2(24, ac0) MF2(25, ac1) MF2(26, ac2) MF2(27, ac3)
      MF2(28, ac0) MF2(29, ac1) MF2(30, ac2) MF2(31, ac3)
    } else {
      // 1. per-wave subset poll: only this wave's 16 producers (4 u64)
      for (;;) {
        u64 f = __hip_atomic_load(fpw, __ATOMIC_RELAXED, __HIP_MEMORY_SCOPE_AGENT);
        bool ok = ((int)(f & 0xFFFF) >= t) && ((int)((f >> 16) & 0xFFFF) >= t) &&
                  ((int)((f >> 32) & 0xFFFF) >= t) && ((int)(f >> 48) >= t);
        if (__all(ok)) break;
      }
      __builtin_amdgcn_sched_barrier(0);
      // 2. stage this wave's 8KB (IDENTITY copy; content already k-major)
      const unsigned short* hsrc = hring + (size_t)t * 65536 + (size_t)g * 16384;
#pragma unroll
      for (int i = 0; i < 8; ++i) {
        int ch = w * 512 + i * 64;            // wave-uniform chunk base
        gload_lds16(hsrc + ((size_t)ch + lane) * 8, Hs + (size_t)ch * 8);
      }
      asm volatile("s_waitcnt vmcnt(0)" ::: "memory");
      __builtin_amdgcn_sched_barrier(0);
      __syncthreads();                        // full-block rendezvous: all staged
      MFH(0, ac0)  MFH(1, ac1)  MFH(2, ac2)  MFH(3, ac3)
      MFH(4, ac0)  MFH(5, ac1)  MFH(6, ac2)  MFH(7, ac3)
      MFH(8, ac0)  MFH(9, ac1)  MFH(10, ac2) MFH(11, ac3)
      MFH(12, ac0) MFH(13, ac1) MFH(14, ac2) MFH(15, ac3)
      MFH(16, ac0) MFH(17, ac1) MFH(18, ac2) MFH(19, ac3)
      MFH(20, ac0) MFH(21, ac1) MFH(22, ac2) MFH(23, ac3)
      MFH(24, ac0) MFH(25, ac1) MFH(26, ac2) MFH(27, ac3)
      MFH(28, ac0) MFH(29, ac1) MFH(30, ac2) MFH(31, ac3)
    }
    f32x4 accs = (ac0 + ac1) + (ac2 + ac3);

    // 3. stage gates (intra-wave): Gs[w][b*17 + lr], b = hi*4+r; lr = s*4+q2
#pragma unroll
    for (int r = 0; r < 4; ++r)
      Gs[w][(hi * 4 + r) * 17 + lr] = accs[r];
    asm volatile("s_waitcnt lgkmcnt(0)" ::: "memory");
    __builtin_amdgcn_sched_barrier(0);

    // 4. cell update for (cb, col): gates from own wave's Gs + gx
    float gi = Gs[w][cb * 17 + 0 + cq]  + bf2f((unsigned short)(gv));
    float gf = Gs[w][cb * 17 + 4 + cq]  + bf2f((unsigned short)(gv >> 16));
    float gg = Gs[w][cb * 17 + 8 + cq]  + bf2f((unsigned short)(gv >> 32));
    float go = Gs[w][cb * 17 + 12 + cq] + bf2f((unsigned short)(gv >> 48));
    float i_ = fsig(gi);
    float f_ = fsig(gf);
    float g_ = tanhf(gg);
    float o_ = fsig(go);
    float cn = f_ * c_reg + i_ * g_;
    float hn = o_ * tanhf(cn);
    c_reg = cn;

    if (t == 511) {
      __builtin_nontemporal_store(hn, &out[((size_t)brow * 512 + t) * 1024 + col]);
      hout[(size_t)brow * 1024 + col] = hn;
      cout[(size_t)brow * 1024 + col] = cn;
    } else {
      // publish h_t: quad packs 4 cols into one u64, write-through, K-MAJOR addr
      unsigned hu = f2bf(hn);
      unsigned v0 = __shfl(hu, (lane & ~3) + 0);
      unsigned v1 = __shfl(hu, (lane & ~3) + 1);
      unsigned v2 = __shfl(hu, (lane & ~3) + 2);
      unsigned v3 = __shfl(hu, (lane & ~3) + 3);
      if ((lane & 3) == 0) {
        u64 pack = (u64)(v0 & 0xFFFF) | ((u64)(v1 & 0xFFFF) << 16)
                 | ((u64)(v2 & 0xFFFF) << 32) | ((u64)(v3 & 0xFFFF) << 48);
        u64* hp;
        if (RING == 2) {
          hp = (u64*)(hring + (size_t)((t + 1) & 1) * 65536
                      + (size_t)brow * 1024 + gt * 16 + w * 4);
        } else {
          // k-major: elem = kchunk*128 + cb*8 + (w&1)*4, kchunk = gt*2 + (w>>1)
          size_t e = (size_t)(gt * 2 + (w >> 1)) * 128 + (size_t)cb * 8 + (size_t)(w & 1) * 4;
          hp = (u64*)(hring + (size_t)(t + 1) * 65536 + (size_t)g * 16384 + e);
        }
        __hip_atomic_store(hp, pack, __ATOMIC_RELAXED, __HIP_MEMORY_SCOPE_AGENT);
      }
      __syncthreads();        // barrier drains vmcnt for all waves
      if (tid == 0)           // RELAXED u16 flag store (group-local)
        __hip_atomic_store(&flags[g * 64 + gt], (unsigned short)(t + 1),
                           __ATOMIC_RELAXED, __HIP_MEMORY_SCOPE_AGENT);
      // out store + next-gx prefetch AFTER the handshake
      __builtin_nontemporal_store(hn, &out[((size_t)brow * 512 + t) * 1024 + col]);
      gv = gbase[(size_t)(t + 1) * 65536 + tid];
    }
  }
}
#undef MF2
#undef MFH
#undef WLOAD
#undef WDECL
#undef R32

extern "C" void kernel_launch(void* const* d_in, const int* in_sizes, int n_in,
                              void* d_out, int out_size, void* d_ws, size_t ws_size,
                              hipStream_t stream) {
  const float* x = (const float*)d_in[0];
  const float* W_emb = (const float*)d_in[1];
  const float* b_emb = (const float*)d_in[2];
  const float* W_ih = (const float*)d_in[3];
  const float* W_hh = (const float*)d_in[4];
  const float* b_ih = (const float*)d_in[5];
  const float* b_hh = (const float*)d_in[6];

  char* ws = (char*)d_ws;
  unsigned short* x_bf    = (unsigned short*)(ws + 0);           // 16,777,216 B
  unsigned short* WembT   = (unsigned short*)(ws + 16777216);    // 262,144 B (bf16 [256,512])
  unsigned short* Wih_bf  = (unsigned short*)(ws + 17039360);    // 4,194,304 B
  unsigned short* Whh_bf  = (unsigned short*)(ws + 21233664);    // 8,388,608 B
  float* b_comb           = (float*)(ws + 29622272);             // 16,384 B
  float* zerob            = (float*)(ws + 29638656);             // 1,024 B
  unsigned short* Wcomb   = (unsigned short*)(ws + 29639680);    // 2,097,152 B (bf16 [4096,256])
  unsigned short* gx3     = (unsigned short*)(ws + 63193088);    // 268,435,456 B
  unsigned short* flags   = (unsigned short*)(ws + 331628544);   // 4,096 B (512 B used)
  unsigned short* hring   = (unsigned short*)(ws + 331632640);   // RING*131,072 B

  const size_t need_ring = 331632640ull + 512ull * 131072ull;    // ~398.7 MB
  const bool big = (ws_size >= need_ring);

  float* out = (float*)d_out;
  float* hout = out + (size_t)64 * 512 * 1024;
  float* cout = hout + 65536;

  k_convert<<<8192, 256, 0, stream>>>(x, x_bf, 2097152);
  k_convert<<<2048, 256, 0, stream>>>(W_ih, Wih_bf, 524288);
  k_convert<<<4096, 256, 0, stream>>>(W_hh, Whh_bf, 1048576);
  k_temb<<<512, 256, 0, stream>>>(W_emb, WembT);
  k_bcomb<<<16, 256, 0, stream>>>(W_ih, b_emb, b_ih, b_hh, b_comb);
  k_init<<<256, 256, 0, stream>>>(hring, flags, zerob);

  // W_comb = W_ih @ W_emb : M=4096, N=256, K=512 (bias = 0)
  k_gemm_bt<0><<<dim3(2, 32), 256, 0, stream>>>(Wih_bf, WembT, zerob, Wcomb, 4096, 256, 512);
  // gx = x @ W_comb^T + b_comb : M=32768, N=4096, K=256, scattered persist layout
  k_gemm_bt<1><<<dim3(32, 256), 256, 0, stream>>>(x_bf, Wcomb, b_comb, gx3, 32768, 4096, 256);

  if (big)
    k_persist<512><<<256, 256, 0, stream>>>(gx3, Whh_bf, hring, flags, out, hout, cout);
  else
    k_persist<2><<<256, 256, 0, stream>>>(gx3, Whh_bf, hring, flags, out, hout, cout);
}

// Round 21
// 1805.511 us; speedup vs baseline: 1.4682x; 1.1367x over previous
//
#include <hip/hip_runtime.h>
#include <stdint.h>

typedef __attribute__((ext_vector_type(8))) short short8;
typedef __attribute__((ext_vector_type(4))) float f32x4;
typedef __attribute__((ext_vector_type(4))) unsigned short ushort4v;
typedef unsigned long long u64;

__device__ inline unsigned short f2bf(float x) {
  union { float f; unsigned u; } v; v.f = x;
  unsigned r = (v.u + 0x7FFFu + ((v.u >> 16) & 1u)) >> 16;
  return (unsigned short)r;
}
__device__ inline float bf2f(unsigned short b) {
  union { unsigned u; float f; } v; v.u = ((unsigned)b) << 16;
  return v.f;
}
__device__ inline float fsig(float x) { return 1.f / (1.f + __expf(-x)); }

__device__ inline void gload_lds16(const void* g, void* l) {
  __builtin_amdgcn_global_load_lds(
      (const __attribute__((address_space(1))) unsigned int*)g,
      (__attribute__((address_space(3))) unsigned int*)l, 16, 0, 0);
}

#define GXPLANE 33554432ull  // u16 elems per s-plane: 512*64*1024

// ---------- elementwise helpers ----------
__global__ void k_convert(const float* __restrict__ src, unsigned short* __restrict__ dst, int n4) {
  int i = blockIdx.x * blockDim.x + threadIdx.x;
  if (i < n4) {
    f32x4 v = *(const f32x4*)(src + (size_t)i * 4);
    ushort4v r;
    r.x = f2bf(v.x); r.y = f2bf(v.y); r.z = f2bf(v.z); r.w = f2bf(v.w);
    *(ushort4v*)(dst + (size_t)i * 4) = r;
  }
}

// x [64][512][256] f32 -> x_bf row-major with row = t*64 + b (t-major)
__global__ void k_convert_x(const float* __restrict__ src, unsigned short* __restrict__ dst) {
  int i = blockIdx.x * blockDim.x + threadIdx.x;   // 2,097,152 quads
  int p = i * 4;
  int b = p >> 17, rem = p & 131071, t = rem >> 8, k = rem & 255;
  f32x4 v = *(const f32x4*)(src + (size_t)p);
  ushort4v r;
  r.x = f2bf(v.x); r.y = f2bf(v.y); r.z = f2bf(v.z); r.w = f2bf(v.w);
  *(ushort4v*)(dst + ((size_t)(t * 64 + b) << 8) + k) = r;
}

// W_emb [512,256] f32 -> WembT [256,512] bf16
__global__ void k_temb(const float* __restrict__ We, unsigned short* __restrict__ WT) {
  int o = blockIdx.x * blockDim.x + threadIdx.x;  // 131072
  int r = o >> 9, e = o & 511;
  WT[o] = f2bf(We[e * 256 + r]);
}

// b_comb[g] = sum_e W_ih[g,e]*b_emb[e] + b_ih[g] + b_hh[g]   (pure f32)
__global__ void k_bcomb(const float* __restrict__ Wih, const float* __restrict__ b_emb,
                        const float* __restrict__ b_ih, const float* __restrict__ b_hh,
                        float* __restrict__ out) {
  int g = blockIdx.x * blockDim.x + threadIdx.x;  // 4096
  const float* row = Wih + (size_t)g * 512;
  float s = 0.f;
  for (int e = 0; e < 512; ++e) s += row[e] * b_emb[e];
  out[g] = s + b_ih[g] + b_hh[g];
}

__global__ void k_init(unsigned short* __restrict__ h0, unsigned short* __restrict__ flags,
                       float* __restrict__ zerob) {
  int i = blockIdx.x * blockDim.x + threadIdx.x;  // 65536 threads
  h0[i] = 0;                                      // ring slot 0 = h_{-1} = 0
  if (i < 256) { flags[i] = 0; zerob[i] = 0.f; }
}

// ---------- bf16 GEMM: C = A @ B^T (+bias), A [M,K], B [N,K], all bf16, f32 accum ----------
// MODE 0: C bf16, natural row order.
// MODE 1: A rows are t-major (row = t*64+b); C scattered to 4 s-planes:
//   idx = s*GXPLANE + ((t*64)+gt)*1024 + g*256 + wv*64 + bb*4 + qq
//   -> per (tile,t,gt) a FULL contiguous 2KB [g][256] slice (no partial lines).
//   XCD-aware block swizzle (nwg % 8 == 0).
template <int MODE>
__global__ __launch_bounds__(256) void k_gemm_bt(
    const unsigned short* __restrict__ A,
    const unsigned short* __restrict__ Bm,
    const float* __restrict__ bias,
    unsigned short* __restrict__ C,
    int M, int N, int K) {
  __shared__ unsigned short As[128 * 32];
  __shared__ unsigned short Bs[128 * 32];
  const int tid = threadIdx.x;

  int bidx = blockIdx.x, bidy = blockIdx.y;
  if (MODE == 1) {
    int bid = blockIdx.y * gridDim.x + blockIdx.x;
    int cpx = (gridDim.x * gridDim.y) >> 3;      // nwg/8 (nwg divisible by 8)
    int swz = (bid & 7) * cpx + (bid >> 3);      // XCD-contiguous chunks
    bidy = swz / gridDim.x;
    bidx = swz % gridDim.x;
  }
  const int m0 = bidy * 128, n0 = bidx * 128;
  const int lane = tid & 63, w = tid >> 6;
  const int wm = (w >> 1) * 64, wn = (w & 1) * 64;

  f32x4 acc[4][4] = {};

  const int ar0 = tid >> 2;
  const int ak = (tid & 3) * 8;
  const unsigned short* Ag0 = A + (size_t)(m0 + ar0) * K + ak;
  const unsigned short* Ag1 = A + (size_t)(m0 + 64 + ar0) * K + ak;
  const unsigned short* Bg0 = Bm + (size_t)(n0 + ar0) * K + ak;
  const unsigned short* Bg1 = Bm + (size_t)(n0 + 64 + ar0) * K + ak;
  unsigned short* Al = As + tid * 8;
  unsigned short* Bl = Bs + tid * 8;

  const int lr = lane & 15, lk = (lane >> 4) * 8;

  for (int k0 = 0; k0 < K; k0 += 32) {
    gload_lds16(Ag0 + k0, Al);
    gload_lds16(Ag1 + k0, Al + 2048);
    gload_lds16(Bg0 + k0, Bl);
    gload_lds16(Bg1 + k0, Bl + 2048);
    __syncthreads();
    short8 a[4], b[4];
#pragma unroll
    for (int i = 0; i < 4; i++) a[i] = *(const short8*)&As[(wm + i * 16 + lr) * 32 + lk];
#pragma unroll
    for (int j = 0; j < 4; j++) b[j] = *(const short8*)&Bs[(wn + j * 16 + lr) * 32 + lk];
#pragma unroll
    for (int i = 0; i < 4; i++)
#pragma unroll
      for (int j = 0; j < 4; j++)
        acc[i][j] = __builtin_amdgcn_mfma_f32_16x16x32_bf16(a[i], b[j], acc[i][j], 0, 0, 0);
    __syncthreads();
  }

  const int lq = (lane >> 4) * 4;
#pragma unroll
  for (int j = 0; j < 4; j++) {
    int col = n0 + wn + j * 16 + lr;
    float bv = bias[col];
#pragma unroll
    for (int i = 0; i < 4; i++) {
      int rowb = m0 + wm + i * 16 + lq;
#pragma unroll
      for (int r = 0; r < 4; r++) {
        int row = rowb + r;
        float v = acc[i][j][r] + bv;
        if (MODE == 1) {
          int t = row >> 6, bglob = row & 63;          // t-major rows
          int gg = bglob >> 4, bb = bglob & 15;
          int s = col >> 10, cc = col & 1023;
          int gtb = cc >> 4, cl = cc & 15;
          int wv = cl >> 2, qq = cl & 3;
          size_t idx = (size_t)s * GXPLANE
                     + ((size_t)t * 64 + (size_t)gtb) * 1024
                     + (size_t)gg * 256 + (size_t)(wv * 64 + bb * 4 + qq);
          C[idx] = f2bf(v);
        } else {
          C[(size_t)row * (size_t)N + col] = f2bf(v);
        }
      }
    }
  }
}

// ---------- persistent LSTM recurrence, batch-group partitioned (R19/R20 form) ----------
#define R32(F) F(0) F(1) F(2) F(3) F(4) F(5) F(6) F(7) \
               F(8) F(9) F(10) F(11) F(12) F(13) F(14) F(15) \
               F(16) F(17) F(18) F(19) F(20) F(21) F(22) F(23) \
               F(24) F(25) F(26) F(27) F(28) F(29) F(30) F(31)
#define WDECL(i) short8 w##i;
#define WLOAD(i) asm volatile("global_load_dwordx4 %0, %1, off offset:%c2" \
                              : "=v"(w##i) : "v"(wbase), "i"((i) * 64));
#define MFH(i, ACC) { \
    short8 a_ = *(const short8*)(HsB + lB + (i) * 1024); \
    ACC = __builtin_amdgcn_mfma_f32_16x16x32_bf16(a_, w##i, ACC, 0, 0, 0); }
#define MF2(i, ACC) { \
    union { u64 d[2]; short8 s; } u_; \
    u_.d[0] = __hip_atomic_load((const u64*)(hrow2 + (i) * 32), __ATOMIC_RELAXED, __HIP_MEMORY_SCOPE_AGENT); \
    u_.d[1] = __hip_atomic_load((const u64*)(hrow2 + (i) * 32 + 4), __ATOMIC_RELAXED, __HIP_MEMORY_SCOPE_AGENT); \
    ACC = __builtin_amdgcn_mfma_f32_16x16x32_bf16(u_.s, w##i, ACC, 0, 0, 0); }

template <int RING>
__global__ __launch_bounds__(256, 1) void k_persist(
    const unsigned short* __restrict__ gx3,   // 4 s-planes (see GEMM MODE1)
    const unsigned short* __restrict__ Whh,   // [4096,1024] bf16
    unsigned short* __restrict__ hring,       // RING slots; k-major content if RING=512
    unsigned short* __restrict__ flags,       // [4][64] u16 epochs
    float* __restrict__ out,                  // [64][512][1024] f32
    float* __restrict__ hout,                 // [64][1024] f32
    float* __restrict__ cout) {               // [64][1024] f32
  __shared__ unsigned short Hs[16384];        // 32 KB group-h stage (k-major content)
  __shared__ float Gs[4][16 * 17 + 4];        // per-wave gate buffers

  const int tid = threadIdx.x;
  const int g = blockIdx.x & 3, gt = blockIdx.x >> 2;
  const int lane = tid & 63, w = tid >> 6;
  const int lr = lane & 15, hi = lane >> 4;

  // ---- W_hh slice in named registers
  const int grow = (lr >> 2) * 1024 + gt * 16 + w * 4 + (lr & 3);
  const unsigned short* wbase = Whh + (size_t)grow * 1024 + hi * 8;
  R32(WDECL)
  R32(WLOAD)
  asm volatile("s_waitcnt vmcnt(0)" ::: "memory");
  __builtin_amdgcn_sched_barrier(0);

  // ---- cell identity: lane = cb*4 + cq (batch cb, col quad-offset cq)
  const int cb = lane >> 2, cq = lane & 3;
  const int col = gt * 16 + w * 4 + cq;
  const int brow = g * 16 + cb;               // global batch row
  float c_reg = 0.f;

  // gx: 4 s-planes; per (t): plane offset t*65536 + gt*1024 + g*256 + tid
  const unsigned short* gp0 = gx3 + (size_t)gt * 1024 + (size_t)g * 256 + tid;
  unsigned short gv0 = gp0[0], gv1 = gp0[GXPLANE], gv2 = gp0[2 * GXPLANE], gv3 = gp0[3 * GXPLANE];

  const char* HsB = (const char*)Hs;
  const int lB = hi * 256 + lr * 16;          // k-major lane byte base

  // per-wave poll pointer: wave w needs flags of producers [w*16,(w+1)*16)
  const u64* fpw = (const u64*)flags + g * 16 + w * 4 + (lane & 3);

  for (int t = 0; t < 512; ++t) {
    f32x4 ac0 = {}, ac1 = {}, ac2 = {}, ac3 = {};
    if (RING == 2) {
      if (w == 0) {
        const u64* fp = (const u64*)flags + g * 16 + lane;  // lanes 0..15 valid
        for (;;) {
          bool ok = true;
          if (lane < 16) {
            u64 f = __hip_atomic_load(fp, __ATOMIC_RELAXED, __HIP_MEMORY_SCOPE_AGENT);
            ok = ((int)(f & 0xFFFF) >= t) && ((int)((f >> 16) & 0xFFFF) >= t) &&
                 ((int)((f >> 32) & 0xFFFF) >= t) && ((int)(f >> 48) >= t);
          }
          if (__all(ok)) break;
        }
      }
      __syncthreads();
      __builtin_amdgcn_sched_barrier(0);
      const unsigned short* hrow2 = hring + (size_t)(t & 1) * 65536
                                  + (size_t)(g * 16 + lr) * 1024 + hi * 8;
      MF2(0, ac0)  MF2(1, ac1)  MF2(2, ac2)  MF2(3, ac3)
      MF2(4, ac0)  MF2(5, ac1)  MF2(6, ac2)  MF2(7, ac3)
      MF2(8, ac0)  MF2(9, ac1)  MF2(10, ac2) MF2(11, ac3)
      MF2(12, ac0) MF2(13, ac1) MF2(14, ac2) MF2(15, ac3)
      MF2(16, ac0) MF2(17, ac1) MF2(18, ac2) MF2(19, ac3)
      MF2(20, ac0) MF2(21, ac1) MF2(22, ac2) MF2(23, ac3)
      MF2(24, ac0) MF2(25, ac1) MF2(26, ac2) MF2(27, ac3)
      MF2(28, ac0) MF2(29, ac1) MF2(30, ac2) MF2(31, ac3)
    } else {
      // 1. per-wave subset poll: only this wave's 16 producers (4 u64)
      for (;;) {
        u64 f = __hip_atomic_load(fpw, __ATOMIC_RELAXED, __HIP_MEMORY_SCOPE_AGENT);
        bool ok = ((int)(f & 0xFFFF) >= t) && ((int)((f >> 16) & 0xFFFF) >= t) &&
                  ((int)((f >> 32) & 0xFFFF) >= t) && ((int)(f >> 48) >= t);
        if (__all(ok)) break;
      }
      __builtin_amdgcn_sched_barrier(0);
      // 2. stage this wave's 8KB (IDENTITY copy; content already k-major)
      const unsigned short* hsrc = hring + (size_t)t * 65536 + (size_t)g * 16384;
#pragma unroll
      for (int i = 0; i < 8; ++i) {
        int ch = w * 512 + i * 64;            // wave-uniform chunk base
        gload_lds16(hsrc + ((size_t)ch + lane) * 8, Hs + (size_t)ch * 8);
      }
      asm volatile("s_waitcnt vmcnt(0)" ::: "memory");
      __builtin_amdgcn_sched_barrier(0);
      __syncthreads();                        // full-block rendezvous: all staged
      MFH(0, ac0)  MFH(1, ac1)  MFH(2, ac2)  MFH(3, ac3)
      MFH(4, ac0)  MFH(5, ac1)  MFH(6, ac2)  MFH(7, ac3)
      MFH(8, ac0)  MFH(9, ac1)  MFH(10, ac2) MFH(11, ac3)
      MFH(12, ac0) MFH(13, ac1) MFH(14, ac2) MFH(15, ac3)
      MFH(16, ac0) MFH(17, ac1) MFH(18, ac2) MFH(19, ac3)
      MFH(20, ac0) MFH(21, ac1) MFH(22, ac2) MFH(23, ac3)
      MFH(24, ac0) MFH(25, ac1) MFH(26, ac2) MFH(27, ac3)
      MFH(28, ac0) MFH(29, ac1) MFH(30, ac2) MFH(31, ac3)
    }
    f32x4 accs = (ac0 + ac1) + (ac2 + ac3);

    // 3. stage gates (intra-wave): Gs[w][b*17 + lr], b = hi*4+r; lr = s*4+q2
#pragma unroll
    for (int r = 0; r < 4; ++r)
      Gs[w][(hi * 4 + r) * 17 + lr] = accs[r];
    asm volatile("s_waitcnt lgkmcnt(0)" ::: "memory");
    __builtin_amdgcn_sched_barrier(0);

    // 4. cell update for (cb, col): gates from own wave's Gs + gx planes
    float gi = Gs[w][cb * 17 + 0 + cq]  + bf2f(gv0);
    float gf = Gs[w][cb * 17 + 4 + cq]  + bf2f(gv1);
    float gg = Gs[w][cb * 17 + 8 + cq]  + bf2f(gv2);
    float go = Gs[w][cb * 17 + 12 + cq] + bf2f(gv3);
    float i_ = fsig(gi);
    float f_ = fsig(gf);
    float g_ = tanhf(gg);
    float o_ = fsig(go);
    float cn = f_ * c_reg + i_ * g_;
    float hn = o_ * tanhf(cn);
    c_reg = cn;

    if (t == 511) {
      __builtin_nontemporal_store(hn, &out[((size_t)brow * 512 + t) * 1024 + col]);
      hout[(size_t)brow * 1024 + col] = hn;
      cout[(size_t)brow * 1024 + col] = cn;
    } else {
      // publish h_t: quad packs 4 cols into one u64, write-through, K-MAJOR addr
      unsigned hu = f2bf(hn);
      unsigned v0 = __shfl(hu, (lane & ~3) + 0);
      unsigned v1 = __shfl(hu, (lane & ~3) + 1);
      unsigned v2 = __shfl(hu, (lane & ~3) + 2);
      unsigned v3 = __shfl(hu, (lane & ~3) + 3);
      if ((lane & 3) == 0) {
        u64 pack = (u64)(v0 & 0xFFFF) | ((u64)(v1 & 0xFFFF) << 16)
                 | ((u64)(v2 & 0xFFFF) << 32) | ((u64)(v3 & 0xFFFF) << 48);
        u64* hp;
        if (RING == 2) {
          hp = (u64*)(hring + (size_t)((t + 1) & 1) * 65536
                      + (size_t)brow * 1024 + gt * 16 + w * 4);
        } else {
          // k-major: elem = kchunk*128 + cb*8 + (w&1)*4, kchunk = gt*2 + (w>>1)
          size_t e = (size_t)(gt * 2 + (w >> 1)) * 128 + (size_t)cb * 8 + (size_t)(w & 1) * 4;
          hp = (u64*)(hring + (size_t)(t + 1) * 65536 + (size_t)g * 16384 + e);
        }
        __hip_atomic_store(hp, pack, __ATOMIC_RELAXED, __HIP_MEMORY_SCOPE_AGENT);
      }
      __syncthreads();        // barrier drains vmcnt for all waves
      if (tid == 0)           // RELAXED u16 flag store (group-local)
        __hip_atomic_store(&flags[g * 64 + gt], (unsigned short)(t + 1),
                           __ATOMIC_RELAXED, __HIP_MEMORY_SCOPE_AGENT);
      // out store + next-gx prefetch AFTER the handshake
      __builtin_nontemporal_store(hn, &out[((size_t)brow * 512 + t) * 1024 + col]);
      const unsigned short* gp = gx3 + (size_t)(t + 1) * 65536 + (size_t)gt * 1024
                               + (size_t)g * 256 + tid;
      gv0 = gp[0]; gv1 = gp[GXPLANE]; gv2 = gp[2 * GXPLANE]; gv3 = gp[3 * GXPLANE];
    }
  }
}
#undef MF2
#undef MFH
#undef WLOAD
#undef WDECL
#undef R32

extern "C" void kernel_launch(void* const* d_in, const int* in_sizes, int n_in,
                              void* d_out, int out_size, void* d_ws, size_t ws_size,
                              hipStream_t stream) {
  const float* x = (const float*)d_in[0];
  const float* W_emb = (const float*)d_in[1];
  const float* b_emb = (const float*)d_in[2];
  const float* W_ih = (const float*)d_in[3];
  const float* W_hh = (const float*)d_in[4];
  const float* b_ih = (const float*)d_in[5];
  const float* b_hh = (const float*)d_in[6];

  char* ws = (char*)d_ws;
  unsigned short* x_bf    = (unsigned short*)(ws + 0);           // 16,777,216 B (t-major rows)
  unsigned short* WembT   = (unsigned short*)(ws + 16777216);    // 262,144 B (bf16 [256,512])
  unsigned short* Wih_bf  = (unsigned short*)(ws + 17039360);    // 4,194,304 B
  unsigned short* Whh_bf  = (unsigned short*)(ws + 21233664);    // 8,388,608 B
  float* b_comb           = (float*)(ws + 29622272);             // 16,384 B
  float* zerob            = (float*)(ws + 29638656);             // 1,024 B
  unsigned short* Wcomb   = (unsigned short*)(ws + 29639680);    // 2,097,152 B (bf16 [4096,256])
  unsigned short* gx3     = (unsigned short*)(ws + 63193088);    // 268,435,456 B (4 s-planes)
  unsigned short* flags   = (unsigned short*)(ws + 331628544);   // 4,096 B (512 B used)
  unsigned short* hring   = (unsigned short*)(ws + 331632640);   // RING*131,072 B

  const size_t need_ring = 331632640ull + 512ull * 131072ull;    // ~398.7 MB
  const bool big = (ws_size >= need_ring);

  float* out = (float*)d_out;
  float* hout = out + (size_t)64 * 512 * 1024;
  float* cout = hout + 65536;

  k_convert_x<<<8192, 256, 0, stream>>>(x, x_bf);
  k_convert<<<2048, 256, 0, stream>>>(W_ih, Wih_bf, 524288);
  k_convert<<<4096, 256, 0, stream>>>(W_hh, Whh_bf, 1048576);
  k_temb<<<512, 256, 0, stream>>>(W_emb, WembT);
  k_bcomb<<<16, 256, 0, stream>>>(W_ih, b_emb, b_ih, b_hh, b_comb);
  k_init<<<256, 256, 0, stream>>>(hring, flags, zerob);

  // W_comb = W_ih @ W_emb : M=4096, N=256, K=512 (bias = 0)
  k_gemm_bt<0><<<dim3(2, 32), 256, 0, stream>>>(Wih_bf, WembT, zerob, Wcomb, 4096, 256, 512);
  // gx = x @ W_comb^T + b_comb : M=32768 (t-major), N=4096, K=256, 4-plane layout
  k_gemm_bt<1><<<dim3(32, 256), 256, 0, stream>>>(x_bf, Wcomb, b_comb, gx3, 32768, 4096, 256);

  if (big)
    k_persist<512><<<256, 256, 0, stream>>>(gx3, Whh_bf, hring, flags, out, hout, cout);
  else
    k_persist<2><<<256, 256, 0, stream>>>(gx3, Whh_bf, hring, flags, out, hout, cout);
}